// Round 2
// baseline (245.464 us; speedup 1.0000x reference)
//
#include <hip/hip_runtime.h>
#include <hip/hip_bf16.h>

// Problem constants
#define BSZ   131072
#define DIM   256
#define BM    32            // rows per block (one 32-row group shared by all 8 waves)
#define NT    512           // 8 waves; wave w handles cols [w*32, w*32+32)
#define GRID  (BSZ / BM)    // 4096 blocks

typedef __attribute__((ext_vector_type(8))) short bf16x8;
typedef __attribute__((ext_vector_type(4))) float f32x4;
typedef __attribute__((ext_vector_type(4))) unsigned short u16x4;

__device__ __forceinline__ unsigned short f2bf(float f) {
  unsigned u = __builtin_bit_cast(unsigned, f);
  return (unsigned short)((u + 0x7FFFu + ((u >> 16) & 1u)) >> 16);
}

__device__ __forceinline__ bf16x8 cvtA(f32x4 lo, f32x4 hi) {
  bf16x8 r;
#pragma unroll
  for (int e = 0; e < 4; ++e) {
    r[e]     = (short)f2bf(lo[e]);
    r[4 + e] = (short)f2bf(hi[e]);
  }
  return r;
}

// ---------------- prep: f32 W -> bf16 W in workspace (linear) ----------------
__global__ void prep_kernel(const float* __restrict__ Wmu, const float* __restrict__ Wsd,
                            unsigned short* __restrict__ wm, unsigned short* __restrict__ wsd) {
  const int i = (blockIdx.x * blockDim.x + threadIdx.x) * 4;  // 16384 threads * 4 = 65536
  f32x4 a = *(const f32x4*)(Wmu + i);
  f32x4 b = *(const f32x4*)(Wsd + i);
  u16x4 pa, pb;
#pragma unroll
  for (int e = 0; e < 4; ++e) { pa[e] = f2bf(a[e]); pb[e] = f2bf(b[e]); }
  *(u16x4*)(wm + i)  = pa;
  *(u16x4*)(wsd + i) = pb;
}

// ---------------- main fused kernel: no LDS staging, no K-loop barriers ----------------
__global__ __launch_bounds__(NT, 4)
void main_kernel(const float* __restrict__ z,
                 const unsigned short* __restrict__ wm,
                 const unsigned short* __restrict__ wsd,
                 const float* __restrict__ bmu,
                 const float* __restrict__ bsd,
                 float* __restrict__ out,
                 double* __restrict__ partials) {
  __shared__ float redbuf[8];

  const int t    = threadIdx.x;
  const int lane = t & 63;
  const int wave = t >> 6;           // 0..7 -> col group
  const int rb   = blockIdx.x * BM;  // row base
  const int cb   = wave * 32;        // col base
  const int lr   = lane & 15;        // row (A) / col (B) within fragment
  const int lk   = (lane >> 4) * 8;  // k base within 32-k step

  // A fragment source: z[rb + m*16 + lr][ks*32 + lk ... +8] (f32)
  const float* za = z + (size_t)(rb + lr) * DIM + lk;
  // B fragment source: w[cb + n*16 + lr][ks*32 + lk ... +8] (bf16)
  const unsigned short* wmb = wm  + (size_t)(cb + lr) * DIM + lk;
  const unsigned short* wsb = wsd + (size_t)(cb + lr) * DIM + lk;

  f32x4 accm[2][2], accl[2][2];
#pragma unroll
  for (int m = 0; m < 2; ++m)
#pragma unroll
    for (int n = 0; n < 2; ++n) { accm[m][n] = (f32x4)0.0f; accl[m][n] = (f32x4)0.0f; }

  // current / next fragment registers
  f32x4 alo[2], ahi[2], nalo[2], nahi[2];
  bf16x8 bmf[2], bsf[2], nbmf[2], nbsf[2];

#pragma unroll
  for (int m = 0; m < 2; ++m) {
    const float* p = za + m * 16 * DIM;
    alo[m] = *(const f32x4*)p;
    ahi[m] = *(const f32x4*)(p + 4);
  }
#pragma unroll
  for (int n = 0; n < 2; ++n) {
    bmf[n] = *(const bf16x8*)(wmb + n * 16 * DIM);
    bsf[n] = *(const bf16x8*)(wsb + n * 16 * DIM);
  }

#pragma unroll
  for (int ks = 0; ks < 8; ++ks) {
    if (ks < 7) {
      const int ko = (ks + 1) * 32;
#pragma unroll
      for (int m = 0; m < 2; ++m) {
        const float* p = za + m * 16 * DIM + ko;
        nalo[m] = *(const f32x4*)p;
        nahi[m] = *(const f32x4*)(p + 4);
      }
#pragma unroll
      for (int n = 0; n < 2; ++n) {
        nbmf[n] = *(const bf16x8*)(wmb + n * 16 * DIM + ko);
        nbsf[n] = *(const bf16x8*)(wsb + n * 16 * DIM + ko);
      }
    }

    bf16x8 af[2];
#pragma unroll
    for (int m = 0; m < 2; ++m) af[m] = cvtA(alo[m], ahi[m]);

#pragma unroll
    for (int n = 0; n < 2; ++n)
#pragma unroll
      for (int m = 0; m < 2; ++m) {
        accm[m][n] = __builtin_amdgcn_mfma_f32_16x16x32_bf16(af[m], bmf[n], accm[m][n], 0, 0, 0);
        accl[m][n] = __builtin_amdgcn_mfma_f32_16x16x32_bf16(af[m], bsf[n], accl[m][n], 0, 0, 0);
      }

    if (ks < 7) {
#pragma unroll
      for (int m = 0; m < 2; ++m) { alo[m] = nalo[m]; ahi[m] = nahi[m]; }
#pragma unroll
      for (int n = 0; n < 2; ++n) { bmf[n] = nbmf[n]; bsf[n] = nbsf[n]; }
    }
  }

  // ---- epilogue: bias + relu + KL + store mu (nontemporal: don't evict W from L2) ----
  float klp = 0.0f;
#pragma unroll
  for (int n = 0; n < 2; ++n) {
    const int col = cb + n * 16 + lr;
    const float bmv = bmu[col];
    const float bsv = bsd[col];
#pragma unroll
    for (int m = 0; m < 2; ++m) {
      const int row0 = rb + m * 16 + (lane >> 4) * 4;
#pragma unroll
      for (int r = 0; r < 4; ++r) {
        float mu = fmaxf(accm[m][n][r] + bmv, 0.0f);
        float ls = fmaxf(accl[m][n][r] + bsv, 0.0f);
        float iv = __expf(-2.0f * ls);
        klp += fmaf(mu * mu, iv, iv) + 2.0f * ls;   // (1+mu^2)*iv + 2*ls; -1 folded below
        __builtin_nontemporal_store(mu, &out[(size_t)(row0 + r) * DIM + col]);
      }
    }
  }
  klp = 0.5f * (klp - 16.0f);   // 16 elements per lane, each owes a -1

  // wave -> block reduction
#pragma unroll
  for (int off = 32; off > 0; off >>= 1) klp += __shfl_down(klp, off);
  if (lane == 0) redbuf[wave] = klp;
  __syncthreads();
  if (t == 0) {
    float s = 0.0f;
#pragma unroll
    for (int i = 0; i < 8; ++i) s += redbuf[i];
    partials[blockIdx.x] = (double)s;
  }
}

// ---------------- finalize: reduce per-block partials -> kl ----------------
__global__ void fin_kernel(const double* __restrict__ partials, float* __restrict__ out) {
  __shared__ double red[256];
  double s = 0.0;
  for (int i = threadIdx.x; i < GRID; i += 256) s += partials[i];
  red[threadIdx.x] = s;
  __syncthreads();
  for (int st = 128; st > 0; st >>= 1) {
    if ((int)threadIdx.x < st) red[threadIdx.x] += red[threadIdx.x + st];
    __syncthreads();
  }
  if (threadIdx.x == 0) out[(size_t)BSZ * DIM] = (float)(red[0] / (double)BSZ);
}

// ---------------- launch ----------------
// workspace layout: [0,32KB) 4096 double partials ; [32KB,+128KB) Wmu bf16 ; then Wsd bf16.
// requires ws_size >= 294912 bytes.
extern "C" void kernel_launch(void* const* d_in, const int* in_sizes, int n_in,
                              void* d_out, int out_size, void* d_ws, size_t ws_size,
                              hipStream_t stream) {
  const float* z   = (const float*)d_in[0];
  const float* Wmu = (const float*)d_in[1];
  const float* bmu = (const float*)d_in[2];
  const float* Wsd = (const float*)d_in[3];
  const float* bsd = (const float*)d_in[4];
  float* out = (float*)d_out;

  double* partials    = (double*)d_ws;
  unsigned short* wm  = (unsigned short*)((char*)d_ws + 32768);
  unsigned short* wsd = wm + DIM * DIM;

  prep_kernel<<<64, 256, 0, stream>>>(Wmu, Wsd, wm, wsd);
  main_kernel<<<GRID, NT, 0, stream>>>(z, wm, wsd, bmu, bsd, out, partials);
  fin_kernel<<<1, 256, 0, stream>>>(partials, out);
}

// Round 3
// 153.588 us; speedup vs baseline: 1.5982x; 1.5982x over previous
//
#include <hip/hip_runtime.h>
#include <hip/hip_bf16.h>

#define BSZ  131072
#define DIM  256
#define BM   64
#define NT   512            // 8 waves
#define GRID (BSZ / BM)     // 2048

typedef __attribute__((ext_vector_type(8))) short bf16x8;
typedef __attribute__((ext_vector_type(4))) float f32x4;
typedef __attribute__((ext_vector_type(4))) unsigned int u32x4;
typedef __attribute__((ext_vector_type(4))) unsigned short u16x4;

// LDS map (81920 B = exactly half of 160 KiB -> 2 blocks/CU):
//  [0,32768)      W buf0 : mat0 [256 rows][4 slots x16B] slot-swizzled; mat1 @ +16384
//  [32768,65536)  W buf1
//  [65536,73728)  z buf0 : [64 rows][8 units x16B] f32, unit-swizzled
//  [73728,81920)  z buf1
#define WBUF(b) ((b) * 32768)
#define ZBUF(b) (65536 + (b) * 8192)

__device__ __forceinline__ unsigned short f2bf(float f) {
  unsigned u = __builtin_bit_cast(unsigned, f);
  return (unsigned short)((u + 0x7FFFu + ((u >> 16) & 1u)) >> 16);
}
__device__ __forceinline__ unsigned cvt_pk(float lo, float hi) {
  unsigned r;
  asm("v_cvt_pk_bf16_f32 %0, %1, %2" : "=v"(r) : "v"(lo), "v"(hi));
  return r;
}

// ---------------- prep: f32 W -> bf16 W in workspace (linear row-major) ----------------
__global__ void prep_kernel(const float* __restrict__ Wmu, const float* __restrict__ Wsd,
                            unsigned short* __restrict__ wm, unsigned short* __restrict__ wsd) {
  const int i = (blockIdx.x * blockDim.x + threadIdx.x) * 4;
  f32x4 a = *(const f32x4*)(Wmu + i);
  f32x4 b = *(const f32x4*)(Wsd + i);
  u16x4 pa, pb;
#pragma unroll
  for (int e = 0; e < 4; ++e) { pa[e] = f2bf(a[e]); pb[e] = f2bf(b[e]); }
  *(u16x4*)(wm + i)  = pa;
  *(u16x4*)(wsd + i) = pb;
}

// ---------------- main fused kernel ----------------
__global__ __launch_bounds__(NT, 4)
void main_kernel(const float* __restrict__ z,
                 const unsigned short* __restrict__ wm,
                 const unsigned short* __restrict__ wsd,
                 const float* __restrict__ bmu,
                 const float* __restrict__ bsd,
                 float* __restrict__ out,
                 float* __restrict__ partials) {
  __shared__ unsigned char smem[81920];
  const int t = threadIdx.x, lane = t & 63, w = t >> 6;
  const int bm = blockIdx.x;

  // ---- z DMA source: lane covers tile row r=w*8+(lane>>3), phys slot lane&7 holds
  //      logical unit u = (lane&7)^(r&7); r&7 == lane>>3 ----
  const int zr = w * 8 + (lane >> 3);
  const int zu = (lane & 7) ^ (lane >> 3);
  const float* zsrc = z + (size_t)(bm * BM + zr) * DIM + zu * 4;   // + it*32

  // ---- W DMA source: issue i covers rows w*32+(i&1)*16+(lane>>2); phys slot lane&3
  //      holds logical slot s=(lane&3)^(row&3), row&3 == (lane>>2)&3 ----
  const int wj  = lane >> 2;
  const int wsl = (lane & 3) ^ ((lane >> 2) & 3);

  // ---- fragment read offsets ----
  // A (z, f32): row m*16+(lane&15); logical units 2s,2s+1 (s=lane>>4) at phys ^ (row&7)
  const int u1    = ((lane >> 4) << 1) ^ (lane & 7);
  const int aoff1 = (lane & 15) * 128 + u1 * 16;
  const int aoff2 = (lane & 15) * 128 + (u1 ^ 1) * 16;
  // B (W): row j=w*32+n*16+(lane&15); logical slot lane>>4 at phys ^ (j&3), j&3==lane&3
  const int boff  = w * 2048 + (lane & 15) * 64 + (((lane >> 4) ^ (lane & 3)) << 4);

  f32x4 accm[4][2], accl[4][2];
#pragma unroll
  for (int m = 0; m < 4; ++m)
#pragma unroll
    for (int n = 0; n < 2; ++n) { accm[m][n] = (f32x4)0.0f; accl[m][n] = (f32x4)0.0f; }

  auto issueW = [&](int it) {
#pragma unroll
    for (int i = 0; i < 4; ++i) {
      const unsigned short* src = (i >= 2 ? wsd : wm)
          + (size_t)(w * 32 + (i & 1) * 16 + wj) * DIM + it * 32 + wsl * 8;
      __builtin_amdgcn_global_load_lds((const void*)src,
          (void*)(smem + WBUF(it & 1) + (i >> 1) * 16384 + (w * 2 + (i & 1)) * 1024),
          16, 0, 0);
    }
  };
  auto issueZ = [&](int it) {
    __builtin_amdgcn_global_load_lds((const void*)(zsrc + it * 32),
        (void*)(smem + ZBUF(it & 1) + w * 1024), 16, 0, 0);
  };

  // ---- prologue: W(0), z(0), z(1) in flight; wait all but z(1) ----
  issueW(0);
  issueZ(0);
  issueZ(1);
  asm volatile("s_waitcnt vmcnt(1)" ::: "memory");
  __builtin_amdgcn_sched_barrier(0);
  __builtin_amdgcn_s_barrier();

  // ---- K loop: 8 iterations, fully unrolled, counted vmcnt, raw barriers ----
#pragma unroll
  for (int it = 0; it < 8; ++it) {
    if (it < 7) issueW(it + 1);            // -> wbuf[(it+1)&1], readers finished at it-1

    const unsigned char* zb = smem + ZBUF(it & 1);
    const unsigned char* wb = smem + WBUF(it & 1);

    f32x4 alo[4], ahi[4];
#pragma unroll
    for (int m = 0; m < 4; ++m) {
      alo[m] = *(const f32x4*)(zb + m * 2048 + aoff1);
      ahi[m] = *(const f32x4*)(zb + m * 2048 + aoff2);
    }
    bf16x8 bmf[2], bsf[2];
#pragma unroll
    for (int n = 0; n < 2; ++n) {
      bmf[n] = *(const bf16x8*)(wb + n * 1024 + boff);
      bsf[n] = *(const bf16x8*)(wb + 16384 + n * 1024 + boff);
    }
    bf16x8 af[4];
#pragma unroll
    for (int m = 0; m < 4; ++m) {
      u32x4 p;
      p[0] = cvt_pk(alo[m][0], alo[m][1]);
      p[1] = cvt_pk(alo[m][2], alo[m][3]);
      p[2] = cvt_pk(ahi[m][0], ahi[m][1]);
      p[3] = cvt_pk(ahi[m][2], ahi[m][3]);
      af[m] = __builtin_bit_cast(bf16x8, p);
    }

    // all waves' LDS reads of this z buffer retired -> safe to DMA over it
    asm volatile("s_waitcnt lgkmcnt(0)" ::: "memory");
    __builtin_amdgcn_sched_barrier(0);
    __builtin_amdgcn_s_barrier();
    if (it < 6) issueZ(it + 2);            // -> zbuf[it&1], just-freed buffer

#pragma unroll
    for (int n = 0; n < 2; ++n)
#pragma unroll
      for (int m = 0; m < 4; ++m) {
        accm[m][n] = __builtin_amdgcn_mfma_f32_16x16x32_bf16(af[m], bmf[n], accm[m][n], 0, 0, 0);
        accl[m][n] = __builtin_amdgcn_mfma_f32_16x16x32_bf16(af[m], bsf[n], accl[m][n], 0, 0, 0);
      }

    // tile it+1 ready; leave newest z prefetch in flight (never vmcnt(0) mid-loop)
    if (it < 6) {
      asm volatile("s_waitcnt vmcnt(1)" ::: "memory");   // in flight: z(it+1),W(it+1)x4,z(it+2)
      __builtin_amdgcn_sched_barrier(0);
    } else if (it == 6) {
      asm volatile("s_waitcnt vmcnt(0)" ::: "memory");   // drain z(7), W(7)
      __builtin_amdgcn_sched_barrier(0);
    }
    if (it < 7) __builtin_amdgcn_s_barrier();
  }

  // ---- epilogue: bias + relu + KL + nontemporal store of mu ----
  float klp = 0.0f;
#pragma unroll
  for (int n = 0; n < 2; ++n) {
    const int col = w * 32 + n * 16 + (lane & 15);
    const float bm_ = bmu[col];
    const float bs_ = bsd[col];
#pragma unroll
    for (int m = 0; m < 4; ++m) {
      const int row0 = bm * BM + m * 16 + (lane >> 4) * 4;
#pragma unroll
      for (int r = 0; r < 4; ++r) {
        float mu = fmaxf(accm[m][n][r] + bm_, 0.0f);
        float ls = fmaxf(accl[m][n][r] + bs_, 0.0f);
        float iv = __expf(-2.0f * ls);
        klp += fmaf(mu * mu, iv, iv) + 2.0f * ls;   // (1+mu^2)*iv + 2*ls; -1 folded below
        __builtin_nontemporal_store(mu, &out[(size_t)(row0 + r) * DIM + col]);
      }
    }
  }
  klp = 0.5f * (klp - 32.0f);   // 32 elements per lane

#pragma unroll
  for (int off = 32; off; off >>= 1) klp += __shfl_down(klp, off);
  __syncthreads();                                   // iter-7 reads done; reuse zbuf0
  if (lane == 0) ((float*)(smem + ZBUF(0)))[w] = klp;
  __syncthreads();
  if (t == 0) {
    float s = 0.0f;
#pragma unroll
    for (int i = 0; i < 8; ++i) s += ((float*)(smem + ZBUF(0)))[i];
    partials[bm] = s;
  }
}

// ---------------- finalize: reduce per-block partials -> kl ----------------
__global__ void fin_kernel(const float* __restrict__ partials, float* __restrict__ out) {
  __shared__ double red[256];
  double s = 0.0;
  for (int i = threadIdx.x; i < GRID; i += 256) s += (double)partials[i];
  red[threadIdx.x] = s;
  __syncthreads();
  for (int st = 128; st > 0; st >>= 1) {
    if ((int)threadIdx.x < st) red[threadIdx.x] += red[threadIdx.x + st];
    __syncthreads();
  }
  if (threadIdx.x == 0) out[(size_t)BSZ * DIM] = (float)(red[0] / (double)BSZ);
}

// ---------------- launch ----------------
// ws layout: [0,8192) float partials[2048]; [8192,+128K) Wmu bf16; then Wsd bf16.
// total 270336 B (< R1-proven 278528).
extern "C" void kernel_launch(void* const* d_in, const int* in_sizes, int n_in,
                              void* d_out, int out_size, void* d_ws, size_t ws_size,
                              hipStream_t stream) {
  const float* z   = (const float*)d_in[0];
  const float* Wmu = (const float*)d_in[1];
  const float* bmu = (const float*)d_in[2];
  const float* Wsd = (const float*)d_in[3];
  const float* bsd = (const float*)d_in[4];
  float* out = (float*)d_out;

  float* partials     = (float*)d_ws;
  unsigned short* wm  = (unsigned short*)((char*)d_ws + 8192);
  unsigned short* wsd = wm + DIM * DIM;

  prep_kernel<<<64, 256, 0, stream>>>(Wmu, Wsd, wm, wsd);
  main_kernel<<<GRID, NT, 0, stream>>>(z, wm, wsd, bmu, bsd, out, partials);
  fin_kernel<<<1, 256, 0, stream>>>(partials, out);
}

// Round 5
// 83.854 us; speedup vs baseline: 2.9273x; 1.8316x over previous
//
#include <hip/hip_runtime.h>
#include <hip/hip_bf16.h>

#define BSZ  131072
#define DIM  256
#define BM   64
#define NT   512            // 8 waves; wave w owns output cols [w*32, w*32+32)
#define GRID (BSZ / BM)     // 2048

typedef __attribute__((ext_vector_type(8))) short bf16x8;
typedef __attribute__((ext_vector_type(4))) float f32x4;
typedef __attribute__((ext_vector_type(2))) unsigned int u32x2;
typedef __attribute__((ext_vector_type(4))) unsigned short u16x4;

// LDS map (73728 B -> 2 blocks/CU):
//  Wbuf b @ b*32768 : [2 mats][256 rows][32 k bf16 = 64B] linear
//  zbuf b @ 65536 + b*4096 : [64 rows][32 k bf16 = 64B] linear
#define WBUF(b) ((b) * 32768)
#define ZBUF(b) (65536 + (b) * 4096)

__device__ __forceinline__ unsigned short f2bf(float f) {
  unsigned u = __builtin_bit_cast(unsigned, f);
  return (unsigned short)((u + 0x7FFFu + ((u >> 16) & 1u)) >> 16);
}
__device__ __forceinline__ unsigned cvt_pk(float lo, float hi) {
  unsigned r;
  asm("v_cvt_pk_bf16_f32 %0, %1, %2" : "=v"(r) : "v"(lo), "v"(hi));
  return r;
}

// ---------------- prep: f32 W -> bf16 W, transposed to K-major wT[kb][j][32] ----------------
__global__ void prep_kernel(const float* __restrict__ Wmu, const float* __restrict__ Wsd,
                            unsigned short* __restrict__ wm, unsigned short* __restrict__ wsd) {
  const int tg = blockIdx.x * 256 + threadIdx.x;   // 16384 threads
  const int j  = tg >> 6, kq = tg & 63;            // row j, k-quad kq (k0 = kq*4)
  const int dst = ((kq >> 3) << 13) + (j << 5) + ((kq & 7) << 2);  // kb*8192 + j*32 + kk
  f32x4 a = *(const f32x4*)(Wmu + j * 256 + kq * 4);
  f32x4 b = *(const f32x4*)(Wsd + j * 256 + kq * 4);
  u16x4 pa, pb;
#pragma unroll
  for (int e = 0; e < 4; ++e) { pa[e] = f2bf(a[e]); pb[e] = f2bf(b[e]); }
  *(u16x4*)(wm + dst)  = pa;
  *(u16x4*)(wsd + dst) = pb;
}

// ---------------- main fused kernel ----------------
__global__ __launch_bounds__(NT, 4)
void main_kernel(const float* __restrict__ z,
                 const unsigned short* __restrict__ wm,
                 const unsigned short* __restrict__ wsd,
                 const float* __restrict__ bmu,
                 const float* __restrict__ bsd,
                 float* __restrict__ out,
                 float* __restrict__ partials) {
  __shared__ unsigned char smem[73728];
  __shared__ float redbuf[8];
  const int t = threadIdx.x, lane = t & 63, w = t >> 6;
  const int bm = blockIdx.x;

  // z global source (coalesced: 8 lanes x 16B contiguous per row)
  const float* zsrc = z + (size_t)(bm * BM + (t >> 3)) * DIM + (t & 7) * 4;
  const int zwoff = (t >> 3) * 64 + (t & 7) * 8;            // z ds_write byte offset
  // fragment read offsets (linear, bank-uniform)
  const int aoffW = w * 2048 + (lane & 15) * 64 + ((lane >> 4) << 4);  // + mat*16384 + mi*1024
  const int boffZ = (lane & 15) * 64 + ((lane >> 4) << 4);             // + nj*1024

  f32x4 accm[2][4], accl[2][4];   // [mi][nj]
#pragma unroll
  for (int mi = 0; mi < 2; ++mi)
#pragma unroll
    for (int nj = 0; nj < 4; ++nj) { accm[mi][nj] = (f32x4)0.0f; accl[mi][nj] = (f32x4)0.0f; }

  f32x4 zreg[2];

  // Each wave DMAs its own 2x1KB per matrix (rows w*32..w*32+32), self-consumed.
  // PER-LANE global src: lane covers 16B at src + lane*8 elems (R4 bug: this was uniform).
  auto issueW = [&](int kb, int b) {
#pragma unroll
    for (int m = 0; m < 2; ++m)
#pragma unroll
      for (int h = 0; h < 2; ++h) {
        const unsigned short* src = (m ? wsd : wm)
            + (kb << 13) + (w << 10) + (h << 9) + lane * 8;
        __builtin_amdgcn_global_load_lds((const void*)src,
            (void*)(smem + WBUF(b) + m * 16384 + (w << 11) + (h << 10)), 16, 0, 0);
      }
  };

  // ---- prologue: queue = [W0 x4, Z0, Z1] ----
  issueW(0, 0);
  __builtin_amdgcn_sched_barrier(0);
  zreg[0] = *(const f32x4*)zsrc;
  zreg[1] = *(const f32x4*)(zsrc + 32);
  __builtin_amdgcn_sched_barrier(0);
  asm volatile("s_waitcnt vmcnt(1)" ::: "memory");   // drain W0 x4 + Z0; Z1 stays in flight
  __builtin_amdgcn_sched_barrier(0);
  {
    u32x2 p;
    p[0] = cvt_pk(zreg[0][0], zreg[0][1]);
    p[1] = cvt_pk(zreg[0][2], zreg[0][3]);
    *(u32x2*)(smem + ZBUF(0) + zwoff) = p;
  }
  asm volatile("s_waitcnt lgkmcnt(0)" ::: "memory");
  __builtin_amdgcn_sched_barrier(0);
  __builtin_amdgcn_s_barrier();

  // ---- K loop: 8 iterations, fully unrolled, 1 barrier/iter, counted vmcnt ----
#pragma unroll
  for (int it = 0; it < 8; ++it) {
    // ensure W(it) landed (self-DMA'd last iter). it==0 covered by prologue drain.
    if (it >= 1 && it <= 6) {
      asm volatile("s_waitcnt vmcnt(1)" ::: "memory");   // drains W(it) x4; newest z stays
    } else if (it == 7) {
      asm volatile("s_waitcnt vmcnt(0)" ::: "memory");
    }
    __builtin_amdgcn_sched_barrier(0);

    if (it < 7) issueW(it + 1, (it + 1) & 1);
    __builtin_amdgcn_sched_barrier(0);
    if (it < 6) zreg[it & 1] = *(const f32x4*)(zsrc + (it + 2) * 32);
    __builtin_amdgcn_sched_barrier(0);

    const unsigned char* wb = smem + WBUF(it & 1);
    const unsigned char* zb = smem + ZBUF(it & 1);

    bf16x8 zf[4], wfm[2], wfs[2];
#pragma unroll
    for (int nj = 0; nj < 4; ++nj) zf[nj] = *(const bf16x8*)(zb + nj * 1024 + boffZ);
#pragma unroll
    for (int mi = 0; mi < 2; ++mi) {
      wfm[mi] = *(const bf16x8*)(wb + mi * 1024 + aoffW);
      wfs[mi] = *(const bf16x8*)(wb + 16384 + mi * 1024 + aoffW);
    }

#pragma unroll
    for (int mi = 0; mi < 2; ++mi)
#pragma unroll
      for (int nj = 0; nj < 4; ++nj) {
        accm[mi][nj] = __builtin_amdgcn_mfma_f32_16x16x32_bf16(wfm[mi], zf[nj], accm[mi][nj], 0, 0, 0);
        accl[mi][nj] = __builtin_amdgcn_mfma_f32_16x16x32_bf16(wfs[mi], zf[nj], accl[mi][nj], 0, 0, 0);
      }

    if (it < 7) {
      const f32x4 zv = zreg[(it + 1) & 1];   // compiler auto-waits vmcnt for this
      u32x2 p;
      p[0] = cvt_pk(zv[0], zv[1]);
      p[1] = cvt_pk(zv[2], zv[3]);
      *(u32x2*)(smem + ZBUF((it + 1) & 1) + zwoff) = p;
      asm volatile("s_waitcnt lgkmcnt(0)" ::: "memory");
      __builtin_amdgcn_sched_barrier(0);
      __builtin_amdgcn_s_barrier();
    }
  }

  // ---- epilogue: bias + relu + KL + vectorized f32x4 stores ----
  float klp = 0.0f;
#pragma unroll
  for (int mi = 0; mi < 2; ++mi) {
    const int colb = w * 32 + mi * 16 + ((lane >> 4) << 2);
    const f32x4 b4m = *(const f32x4*)(bmu + colb);
    const f32x4 b4s = *(const f32x4*)(bsd + colb);
#pragma unroll
    for (int nj = 0; nj < 4; ++nj) {
      const size_t row = (size_t)(bm * BM + nj * 16 + (lane & 15));
      f32x4 mu4;
#pragma unroll
      for (int r = 0; r < 4; ++r) {
        float mu = fmaxf(accm[mi][nj][r] + b4m[r], 0.0f);
        float ls = fmaxf(accl[mi][nj][r] + b4s[r], 0.0f);
        float iv = __expf(-2.0f * ls);
        klp += fmaf(mu * mu, iv, iv) + 2.0f * ls;   // (1+mu^2)*iv + 2*ls; -1 folded below
        mu4[r] = mu;
      }
      *(f32x4*)(out + row * DIM + colb) = mu4;
    }
  }
  klp = 0.5f * (klp - 32.0f);   // 32 elements per lane

#pragma unroll
  for (int off = 32; off; off >>= 1) klp += __shfl_down(klp, off);
  if (lane == 0) redbuf[w] = klp;
  __syncthreads();
  if (t == 0) {
    float s = 0.0f;
#pragma unroll
    for (int i = 0; i < 8; ++i) s += redbuf[i];
    partials[bm] = s;
  }
}

// ---------------- finalize ----------------
__global__ void fin_kernel(const float* __restrict__ partials, float* __restrict__ out) {
  __shared__ double red[256];
  double s = 0.0;
  for (int i = threadIdx.x; i < GRID; i += 256) s += (double)partials[i];
  red[threadIdx.x] = s;
  __syncthreads();
  for (int st = 128; st > 0; st >>= 1) {
    if ((int)threadIdx.x < st) red[threadIdx.x] += red[threadIdx.x + st];
    __syncthreads();
  }
  if (threadIdx.x == 0) out[(size_t)BSZ * DIM] = (float)(red[0] / (double)BSZ);
}

// ---------------- launch ----------------
// ws: [0,8192) float partials[2048]; [8192,+128K) wT_mu; [139264,+128K) wT_sd. Total 270336 B.
extern "C" void kernel_launch(void* const* d_in, const int* in_sizes, int n_in,
                              void* d_out, int out_size, void* d_ws, size_t ws_size,
                              hipStream_t stream) {
  const float* z   = (const float*)d_in[0];
  const float* Wmu = (const float*)d_in[1];
  const float* bmu = (const float*)d_in[2];
  const float* Wsd = (const float*)d_in[3];
  const float* bsd = (const float*)d_in[4];
  float* out = (float*)d_out;

  float* partials     = (float*)d_ws;
  unsigned short* wm  = (unsigned short*)((char*)d_ws + 8192);
  unsigned short* wsd = wm + DIM * DIM;

  prep_kernel<<<64, 256, 0, stream>>>(Wmu, Wsd, wm, wsd);
  main_kernel<<<GRID, NT, 0, stream>>>(z, wm, wsd, bmu, bsd, out, partials);
  fin_kernel<<<1, 256, 0, stream>>>(partials, out);
}